// Round 3
// baseline (732.486 us; speedup 1.0000x reference)
//
#include <hip/hip_runtime.h>

typedef unsigned short u16;
typedef unsigned int   u32;
typedef __attribute__((ext_vector_type(8))) short short8;
typedef __attribute__((ext_vector_type(4))) float f32x4;

constexpr int B_ = 4, S_ = 4096, DIN_ = 2048, DOUT_ = 8192;
constexpr int M_ = B_ * S_;   // 16384
constexpr int N_ = DOUT_;     // 8192
constexpr int K_ = DIN_;      // 2048
constexpr size_t NW_ = (size_t)DOUT_ * DIN_;  // 16,777,216 weights

#define GPTR(p) ((const __attribute__((address_space(1))) void*)(p))
#define LPTR(p) ((__attribute__((address_space(3))) void*)(p))

#define SB0()   __builtin_amdgcn_sched_barrier(0)
#define BAR()   asm volatile("s_barrier" ::: "memory")
#define LGKM0() asm volatile("s_waitcnt lgkmcnt(0)" ::: "memory")
#define VM4()   asm volatile("s_waitcnt vmcnt(4)" ::: "memory")
#define VM0()   asm volatile("s_waitcnt vmcnt(0)" ::: "memory")

__device__ __forceinline__ u16 f2bf(float f) {
    u32 u = __float_as_uint(f);
    u += 0x7fffu + ((u >> 16) & 1u);   // round-to-nearest-even
    return (u16)(u >> 16);
}

// ---------------------------------------------------------------------------
// Pass 1: deterministic fp64 abs-sum partials.
// ---------------------------------------------------------------------------
__global__ __launch_bounds__(256)
void abssum_kernel(const float* __restrict__ w, double* __restrict__ partials)
{
    const int tid = threadIdx.x;
    const float* base = w + (size_t)blockIdx.x * 16384 + tid * 4;
    double s = 0.0;
#pragma unroll
    for (int i = 0; i < 16; ++i) {
        float4 v = *(const float4*)(base + i * 1024);
        s += (double)fabsf(v.x) + (double)fabsf(v.y)
           + (double)fabsf(v.z) + (double)fabsf(v.w);
    }
#pragma unroll
    for (int o = 32; o; o >>= 1) s += __shfl_xor(s, o, 64);
    __shared__ double red[4];
    if ((tid & 63) == 0) red[tid >> 6] = s;
    __syncthreads();
    if (tid == 0) partials[blockIdx.x] = (red[0] + red[1]) + (red[2] + red[3]);
}

__global__ __launch_bounds__(1024)
void finalize_thr(const double* __restrict__ partials, double* __restrict__ thr)
{
    __shared__ double red[1024];
    const int tid = threadIdx.x;
    red[tid] = partials[tid];
    __syncthreads();
    for (int s = 512; s > 0; s >>= 1) {
        if (tid < s) red[tid] += red[tid + s];
        __syncthreads();
    }
    if (tid == 0) *thr = red[0] * (1.0 / (double)NW_);
}

// ---------------------------------------------------------------------------
// Pass 3: ternarize W -> bf16 {-1,0,+1}; fp64 compare (threshold razor-thin).
// ---------------------------------------------------------------------------
__device__ __forceinline__ u16 tern(float w, double thr) {
    return (fabs((double)w) > thr) ? (w > 0.0f ? (u16)0x3F80u : (u16)0xBF80u)
                                   : (u16)0u;
}

__global__ __launch_bounds__(256)
void ternarize_kernel(const float* __restrict__ w, const double* __restrict__ thr_p,
                      u16* __restrict__ wt)
{
    const double thr = *thr_p;
    const size_t i = ((size_t)blockIdx.x * 256 + threadIdx.x) * 4;
    float4 v = *(const float4*)(w + i);
    union { u16 u[4]; uint2 v2; } p;
    p.u[0] = tern(v.x, thr);
    p.u[1] = tern(v.y, thr);
    p.u[2] = tern(v.z, thr);
    p.u[3] = tern(v.w, thr);
    *(uint2*)(wt + i) = p.v2;
}

// ---------------------------------------------------------------------------
// Pass 4: RMSNorm rows of x (fp32) -> bf16 xn.
// ---------------------------------------------------------------------------
__global__ __launch_bounds__(256)
void rmsnorm_kernel(const float* __restrict__ x, const float* __restrict__ gamma,
                    u16* __restrict__ xn)
{
    const int row = blockIdx.x;
    const int tid = threadIdx.x;
    const float* xr = x + (size_t)row * K_;
    float4 a = *(const float4*)(xr + tid * 8);
    float4 b = *(const float4*)(xr + tid * 8 + 4);
    float s = a.x*a.x + a.y*a.y + a.z*a.z + a.w*a.w
            + b.x*b.x + b.y*b.y + b.z*b.z + b.w*b.w;
#pragma unroll
    for (int o = 32; o; o >>= 1) s += __shfl_xor(s, o, 64);
    __shared__ float red[4];
    if ((tid & 63) == 0) red[tid >> 6] = s;
    __syncthreads();
    const float tot = (red[0] + red[1]) + (red[2] + red[3]);
    const float r = rsqrtf(tot * (1.0f / (float)K_) + 1.1920928955078125e-07f);
    float4 g0 = *(const float4*)(gamma + tid * 8);
    float4 g1 = *(const float4*)(gamma + tid * 8 + 4);
    union { u16 u[8]; uint4 v4; } p;
    p.u[0] = f2bf(a.x * r * g0.x);
    p.u[1] = f2bf(a.y * r * g0.y);
    p.u[2] = f2bf(a.z * r * g0.z);
    p.u[3] = f2bf(a.w * r * g0.w);
    p.u[4] = f2bf(b.x * r * g1.x);
    p.u[5] = f2bf(b.y * r * g1.y);
    p.u[6] = f2bf(b.z * r * g1.z);
    p.u[7] = f2bf(b.w * r * g1.w);
    *(uint4*)(xn + (size_t)row * K_ + tid * 8) = p.v4;
}

// ---------------------------------------------------------------------------
// Pass 5: GEMM  C[M,N] = xn[M,K] @ wt[N,K]^T + bias   (bf16 in, fp32 out)
// 256x256 tile, BK=64, 8 waves (2Mx4N), 8-phase schedule. v3: READ-AHEAD
// rotation — phase p computes the quadrant whose fragments were read in
// phase p-1 (or earlier), so the post-barrier lgkm wait is ~free and the
// MFMA pipe never stalls on same-phase ds_reads.
//
//   phase: reads(buf)        stage                MFMA (operands from)
//   p0   : a0,b0 (buf0)      B-h0 -> buf1 @kt1    Q3(prev T1)   [regs p5-prev]
//   p1   : a1,b1 (buf0)      B-h1 -> buf1 @kt1    Q0(T0)        [p0]
//   p2   : --                A-h0 -> buf0 @kt2    Q1(T0)        [p0,p1]
//   p3   : --                A-h1 -> buf0 @kt2    Q2(T0)        [p1]   +vmcnt
//   p4   : a0,b0 (buf1)      B-h0 -> buf0 @kt2    Q3(T0)        [p1]
//   p5   : a1,b1 (buf1)      B-h1 -> buf0 @kt2    Q0(T1)        [p4]
//   p6   : --                A-h0 -> buf1 @kt3    Q1(T1)        [p4,p5]
//   p7   : --                A-h1 -> buf1 @kt3    Q2(T1)        [p5]   +vmcnt
//   (final Q3 of the last tile peeled after the loop; first Q3 skipped)
//
// Hazard audit: buf-A reads (p0/p1) complete (LGKM0+BAR at p1 tail) before
// buf-A restage (p2). vmcnt(4) at p3 retires the 8 oldest loads = buf1 A
// (prev p6/p7) + buf1 B (p0/p1) before p4's buf1 reads. Tail it drains VM0.
// ---------------------------------------------------------------------------
__global__ __launch_bounds__(512, 2)
void gemm_bt_kernel(const u16* __restrict__ A, const u16* __restrict__ Bt,
                    const float* __restrict__ bias, float* __restrict__ C)
{
    __shared__ u16 sm[65536];          // 128 KiB: A[2][256][64] | B[2][256][64]
    const char* smc = (const char*)sm;

    const int tid  = threadIdx.x;
    const int lane = tid & 63;
    const int wid  = tid >> 6;
    const int wm   = wid >> 2;         // 0..1
    const int wn   = wid & 3;          // 0..3
    const int hi   = lane >> 4;        // 0..3

    // XCD-aware bijective swizzle: 2048 blocks % 8 == 0
    const int swz = (blockIdx.x & 7) * 256 + (blockIdx.x >> 3);
    const int gm0 = (swz >> 5) * 256;  // 64 M-tiles
    const int gn0 = (swz & 31) * 256;  // 32 N-tiles

    // ---- staging geometry (linear LDS dest, pre-swizzled global source) ----
    const int lr8   = lane >> 3;
    const int cswel = ((lane & 7) ^ lr8) * 8;          // swizzled k-elem offset
    const int rbase = wid * 8 + lr8;                   // 0..63
    const u16* gAr = A  + (size_t)(gm0 + rbase) * K_ + cswel;
    const u16* gBr = Bt + (size_t)(gn0 + rbase) * K_ + cswel;

    auto STAGE = [&](const u16* g, int ldsu, int kt) {
        u16* d = sm + ldsu + wid * 512 + lane * 8;
        const u16* s = g + kt;
        __builtin_amdgcn_global_load_lds(GPTR(s),             LPTR(d),        16, 0, 0);
        __builtin_amdgcn_global_load_lds(GPTR(s + 64 * 2048), LPTR(d + 4096), 16, 0, 0);
    };

    // ---- read geometry (unchanged from v2; zero measured conflicts) ----
    const int c0 = ((hi ^ (lane & 7)) << 4);
    const int rowbyteA = (wm * 128 + (lane & 15)) * 128;
    const int rowbyteB = (wn * 64  + (lane & 15)) * 128;

#define RA(bufr, m, kk) (*(const short8*)(smc + (bufr)*32768 + rowbyteA + (m)*2048 + (c0 ^ ((kk) << 6))))
#define RB(bufr, n, kk) (*(const short8*)(smc + 65536 + (bufr)*32768 + rowbyteB + (n)*2048 + (c0 ^ ((kk) << 6))))

    f32x4 acc[8][4] = {};
    short8 a0[4][2], a1[4][2], b0[2][2], b1[2][2];

#define MFMA_BLK(AF, BF, MO, NO)                                                   \
    do {                                                                           \
        _Pragma("unroll") for (int kk = 0; kk < 2; ++kk)                           \
        _Pragma("unroll") for (int m = 0; m < 4; ++m)                              \
        _Pragma("unroll") for (int n = 0; n < 2; ++n)                              \
            acc[m + MO][n + NO] = __builtin_amdgcn_mfma_f32_16x16x32_bf16(         \
                AF[m][kk], BF[n][kk], acc[m + MO][n + NO], 0, 0, 0);               \
    } while (0)

#define READ_A0B0(bufr)                                                            \
    do {                                                                           \
        _Pragma("unroll") for (int m = 0; m < 4; ++m) {                            \
            a0[m][0] = RA(bufr, m, 0); a0[m][1] = RA(bufr, m, 1); }                \
        _Pragma("unroll") for (int n = 0; n < 2; ++n) {                            \
            b0[n][0] = RB(bufr, n, 0); b0[n][1] = RB(bufr, n, 1); }                \
    } while (0)

#define READ_A1B1(bufr)                                                            \
    do {                                                                           \
        _Pragma("unroll") for (int m = 0; m < 4; ++m) {                            \
            a1[m][0] = RA(bufr, m + 4, 0); a1[m][1] = RA(bufr, m + 4, 1); }        \
        _Pragma("unroll") for (int n = 0; n < 2; ++n) {                            \
            b1[n][0] = RB(bufr, n + 2, 0); b1[n][1] = RB(bufr, n + 2, 1); }        \
    } while (0)

#define PH_SYNC()  do { SB0(); BAR(); } while (0)
#define PH_TAIL()  do { SB0(); LGKM0(); SB0(); BAR(); } while (0)
#define PRIO_MFMA(AF, BF, MO, NO)                                                  \
    do { __builtin_amdgcn_s_setprio(1); MFMA_BLK(AF, BF, MO, NO);                  \
         __builtin_amdgcn_s_setprio(0); } while (0)

    // ---- prologue: stage h0..h5 (Kt0 complete + Kt1 A-halves) ----
    STAGE(gAr,          0,     0);      // A h0 buf0 kt0
    STAGE(gAr + 262144, 8192,  0);      // A h1 buf0
    STAGE(gBr,          32768, 0);      // B h0 buf0
    STAGE(gBr + 262144, 40960, 0);      // B h1 buf0
    STAGE(gAr,          16384, 64);     // A h0 buf1 kt64
    STAGE(gAr + 262144, 24576, 64);     // A h1 buf1
    VM4(); SB0(); BAR();

    for (int it = 0; it < 16; ++it) {
        const bool full = (it < 15);
        const int kt1 = (it * 2 + 1) * 64;
        const int kt2 = (it * 2 + 2) * 64;
        const int kt3 = (it * 2 + 3) * 64;

        // ---- p0: read a0,b0 (buf0) | stage B-h0 -> buf1 | MFMA Q3(prev) ----
        READ_A0B0(0);
        STAGE(gBr, 49152, kt1);
        PH_SYNC();
        if (it) PRIO_MFMA(a1, b1, 4, 2);
        PH_TAIL();

        // ---- p1: read a1,b1 (buf0) | stage B-h1 -> buf1 | MFMA Q0(T0) ----
        READ_A1B1(0);
        STAGE(gBr + 262144, 57344, kt1);
        PH_SYNC();
        PRIO_MFMA(a0, b0, 0, 0);
        PH_TAIL();     // LGKM0 here also guarantees buf0 reads done before p2 restage

        // ---- p2: stage A-h0 -> buf0 @kt2 | MFMA Q1(T0) ----
        if (full) STAGE(gAr, 0, kt2);
        PH_SYNC();
        PRIO_MFMA(a0, b1, 0, 2);
        PH_TAIL();

        // ---- p3: stage A-h1 -> buf0 @kt2 | MFMA Q2(T0) | vmcnt ----
        if (full) STAGE(gAr + 262144, 8192, kt2);
        PH_SYNC();
        PRIO_MFMA(a1, b0, 4, 0);
        SB0(); LGKM0();
        if (full) { VM4(); } else { VM0(); }
        SB0(); BAR();

        // ---- p4: read a0,b0 (buf1) | stage B-h0 -> buf0 | MFMA Q3(T0) ----
        READ_A0B0(1);
        if (full) STAGE(gBr, 32768, kt2);
        PH_SYNC();
        PRIO_MFMA(a1, b1, 4, 2);
        PH_TAIL();

        // ---- p5: read a1,b1 (buf1) | stage B-h1 -> buf0 | MFMA Q0(T1) ----
        READ_A1B1(1);
        if (full) STAGE(gBr + 262144, 40960, kt2);
        PH_SYNC();
        PRIO_MFMA(a0, b0, 0, 0);
        PH_TAIL();     // buf1 reads done before p6 restage

        // ---- p6: stage A-h0 -> buf1 @kt3 | MFMA Q1(T1) ----
        if (full) STAGE(gAr, 16384, kt3);
        PH_SYNC();
        PRIO_MFMA(a0, b1, 0, 2);
        PH_TAIL();

        // ---- p7: stage A-h1 -> buf1 @kt3 | MFMA Q2(T1) | vmcnt ----
        if (full) STAGE(gAr + 262144, 24576, kt3);
        PH_SYNC();
        PRIO_MFMA(a1, b0, 4, 0);
        SB0(); LGKM0();
        if (full) { VM4(); }
        SB0(); BAR();
    }

    // ---- peeled final quadrant: Q3 of tile 31 (operands read at it=15 p5) ----
    PRIO_MFMA(a1, b1, 4, 2);

    // ---- epilogue: C/D layout col=lane&15, row=hi*4+i ----
    const int orow0 = gm0 + wm * 128 + hi * 4;
    const int ocol0 = gn0 + wn * 64 + (lane & 15);
#pragma unroll
    for (int n = 0; n < 4; ++n) {
        const float bvv = bias[ocol0 + n * 16];
#pragma unroll
        for (int m = 0; m < 8; ++m) {
#pragma unroll
            for (int i = 0; i < 4; ++i) {
                C[(size_t)(orow0 + m * 16 + i) * N_ + (ocol0 + n * 16)] = acc[m][n][i] + bvv;
            }
        }
    }
#undef RA
#undef RB
#undef MFMA_BLK
#undef READ_A0B0
#undef READ_A1B1
#undef PH_SYNC
#undef PH_TAIL
#undef PRIO_MFMA
}

// ---------------------------------------------------------------------------
// Workspace layout (bytes):
//   [0,8)            : thr (double)
//   [1024, 9216)     : 1024 fp64 partials
//   [16384, +32MiB)  : wt  bf16 [N=8192][K=2048]
//   [wt_end, +64MiB) : xn  bf16 [M=16384][K=2048]
// ---------------------------------------------------------------------------
extern "C" void kernel_launch(void* const* d_in, const int* in_sizes, int n_in,
                              void* d_out, int out_size, void* d_ws, size_t ws_size,
                              hipStream_t stream)
{
    const float* x     = (const float*)d_in[0];
    const float* w     = (const float*)d_in[1];
    const float* bias  = (const float*)d_in[2];
    const float* gamma = (const float*)d_in[3];
    float* out = (float*)d_out;

    char* ws = (char*)d_ws;
    double* thr      = (double*)(ws);
    double* partials = (double*)(ws + 1024);
    u16*    wt       = (u16*)(ws + 16384);
    u16*    xn       = (u16*)(ws + 16384 + NW_ * 2);

    abssum_kernel   <<<1024,  256,  0, stream>>>(w, partials);
    finalize_thr    <<<1,     1024, 0, stream>>>(partials, thr);
    ternarize_kernel<<<16384, 256,  0, stream>>>(w, thr, wt);
    rmsnorm_kernel  <<<M_,    256,  0, stream>>>(x, gamma, xn);
    gemm_bt_kernel  <<<(M_/256)*(N_/256), 512, 0, stream>>>(xn, wt, bias, out);
}

// Round 4
// 619.722 us; speedup vs baseline: 1.1820x; 1.1820x over previous
//
#include <hip/hip_runtime.h>

typedef unsigned short u16;
typedef unsigned int   u32;
typedef __attribute__((ext_vector_type(8))) short short8;
typedef __attribute__((ext_vector_type(4))) float f32x4;

constexpr int B_ = 4, S_ = 4096, DIN_ = 2048, DOUT_ = 8192;
constexpr int M_ = B_ * S_;   // 16384
constexpr int N_ = DOUT_;     // 8192
constexpr int K_ = DIN_;      // 2048
constexpr size_t NW_ = (size_t)DOUT_ * DIN_;  // 16,777,216 weights

#define GPTR(p) ((const __attribute__((address_space(1))) void*)(p))
#define LPTR(p) ((__attribute__((address_space(3))) void*)(p))

#define SB0()   __builtin_amdgcn_sched_barrier(0)
#define BAR()   asm volatile("s_barrier" ::: "memory")
#define LGKM0() asm volatile("s_waitcnt lgkmcnt(0)" ::: "memory")
#define VM4()   asm volatile("s_waitcnt vmcnt(4)" ::: "memory")
#define VM0()   asm volatile("s_waitcnt vmcnt(0)" ::: "memory")

__device__ __forceinline__ u16 f2bf(float f) {
    u32 u = __float_as_uint(f);
    u += 0x7fffu + ((u >> 16) & 1u);   // round-to-nearest-even
    return (u16)(u >> 16);
}

// ---------------------------------------------------------------------------
// Pass 1: deterministic fp64 abs-sum partials.
// ---------------------------------------------------------------------------
__global__ __launch_bounds__(256)
void abssum_kernel(const float* __restrict__ w, double* __restrict__ partials)
{
    const int tid = threadIdx.x;
    const float* base = w + (size_t)blockIdx.x * 16384 + tid * 4;
    double s = 0.0;
#pragma unroll
    for (int i = 0; i < 16; ++i) {
        float4 v = *(const float4*)(base + i * 1024);
        s += (double)fabsf(v.x) + (double)fabsf(v.y)
           + (double)fabsf(v.z) + (double)fabsf(v.w);
    }
#pragma unroll
    for (int o = 32; o; o >>= 1) s += __shfl_xor(s, o, 64);
    __shared__ double red[4];
    if ((tid & 63) == 0) red[tid >> 6] = s;
    __syncthreads();
    if (tid == 0) partials[blockIdx.x] = (red[0] + red[1]) + (red[2] + red[3]);
}

__global__ __launch_bounds__(1024)
void finalize_thr(const double* __restrict__ partials, double* __restrict__ thr)
{
    __shared__ double red[1024];
    const int tid = threadIdx.x;
    red[tid] = partials[tid];
    __syncthreads();
    for (int s = 512; s > 0; s >>= 1) {
        if (tid < s) red[tid] += red[tid + s];
        __syncthreads();
    }
    if (tid == 0) *thr = red[0] * (1.0 / (double)NW_);
}

// ---------------------------------------------------------------------------
// Pass 3: ternarize W -> bf16 {-1,0,+1}; fp64 compare (threshold razor-thin).
// ---------------------------------------------------------------------------
__device__ __forceinline__ u16 tern(float w, double thr) {
    return (fabs((double)w) > thr) ? (w > 0.0f ? (u16)0x3F80u : (u16)0xBF80u)
                                   : (u16)0u;
}

__global__ __launch_bounds__(256)
void ternarize_kernel(const float* __restrict__ w, const double* __restrict__ thr_p,
                      u16* __restrict__ wt)
{
    const double thr = *thr_p;
    const size_t i = ((size_t)blockIdx.x * 256 + threadIdx.x) * 4;
    float4 v = *(const float4*)(w + i);
    union { u16 u[4]; uint2 v2; } p;
    p.u[0] = tern(v.x, thr);
    p.u[1] = tern(v.y, thr);
    p.u[2] = tern(v.z, thr);
    p.u[3] = tern(v.w, thr);
    *(uint2*)(wt + i) = p.v2;
}

// ---------------------------------------------------------------------------
// Pass 4: RMSNorm rows of x (fp32) -> bf16 xn.
// ---------------------------------------------------------------------------
__global__ __launch_bounds__(256)
void rmsnorm_kernel(const float* __restrict__ x, const float* __restrict__ gamma,
                    u16* __restrict__ xn)
{
    const int row = blockIdx.x;
    const int tid = threadIdx.x;
    const float* xr = x + (size_t)row * K_;
    float4 a = *(const float4*)(xr + tid * 8);
    float4 b = *(const float4*)(xr + tid * 8 + 4);
    float s = a.x*a.x + a.y*a.y + a.z*a.z + a.w*a.w
            + b.x*b.x + b.y*b.y + b.z*b.z + b.w*b.w;
#pragma unroll
    for (int o = 32; o; o >>= 1) s += __shfl_xor(s, o, 64);
    __shared__ float red[4];
    if ((tid & 63) == 0) red[tid >> 6] = s;
    __syncthreads();
    const float tot = (red[0] + red[1]) + (red[2] + red[3]);
    const float r = rsqrtf(tot * (1.0f / (float)K_) + 1.1920928955078125e-07f);
    float4 g0 = *(const float4*)(gamma + tid * 8);
    float4 g1 = *(const float4*)(gamma + tid * 8 + 4);
    union { u16 u[8]; uint4 v4; } p;
    p.u[0] = f2bf(a.x * r * g0.x);
    p.u[1] = f2bf(a.y * r * g0.y);
    p.u[2] = f2bf(a.z * r * g0.z);
    p.u[3] = f2bf(a.w * r * g0.w);
    p.u[4] = f2bf(b.x * r * g1.x);
    p.u[5] = f2bf(b.y * r * g1.y);
    p.u[6] = f2bf(b.z * r * g1.z);
    p.u[7] = f2bf(b.w * r * g1.w);
    *(uint4*)(xn + (size_t)row * K_ + tid * 8) = p.v4;
}

// ---------------------------------------------------------------------------
// Pass 5: GEMM  C[M,N] = xn[M,K] @ wt[N,K]^T + bias   (bf16 in, fp32 out)
// 256x256 tile, BK=64, 8 waves (2Mx4N), 8-phase schedule.
// v4 = v2 skeleton (identical staging/barriers/vmcnt, race-audited) with
// ds_reads redistributed 12/8/4/0 per K-tile so LDS drain and MFMA balance
// per phase (v2's 12/12/0/0 made read-phases LDS-drain-bound while the
// no-read phases left LDS idle). No loop-carried fragment registers (the
// v3 rotation caused WAR renaming -> scratch spill: WRITE_SIZE +278 MB).
//
//   phase: stage                 reads(buf)     MFMA (same/earlier-phase regs)
//   p0   : B-h0 -> buf1 @kt1     a0,b0 (buf0)   Q0(a0,b0)
//   p1   : B-h1 -> buf1 @kt1     a1    (buf0)   Q2(a1,b0)
//   p2   : A-h0 -> buf0 @kt2     b1    (buf0)   Q1(a0,b1)
//   p3   : A-h1 -> buf0 @kt2     --             Q3(a1,b1)   +vmcnt(4)
//   p4   : B-h0 -> buf0 @kt2     a0,b0 (buf1)   Q0
//   p5   : B-h1 -> buf0 @kt2     a1    (buf1)   Q2
//   p6   : A-h0 -> buf1 @kt3     b1    (buf1)   Q1
//   p7   : A-h1 -> buf1 @kt3     --             Q3          +vmcnt(4)
//
// Hazard audit: buf0-A reads end p1 (p1 tail LGKM0+BAR) before buf0-A
// restage p2; buf0-B reads end p2 before buf0-B restage p4; buf1 reads
// start p4 behind p3's VM4+BAR which retires exactly buf1's 4 half-tiles
// (A from prev p6/p7, B from p0/p1). Tail iteration drains VM0 at p3.
// ---------------------------------------------------------------------------
__global__ __launch_bounds__(512, 2)
void gemm_bt_kernel(const u16* __restrict__ A, const u16* __restrict__ Bt,
                    const float* __restrict__ bias, float* __restrict__ C)
{
    __shared__ u16 sm[65536];          // 128 KiB: A[2][256][64] | B[2][256][64]
    const char* smc = (const char*)sm;

    const int tid  = threadIdx.x;
    const int lane = tid & 63;
    const int wid  = tid >> 6;
    const int wm   = wid >> 2;         // 0..1
    const int wn   = wid & 3;          // 0..3
    const int hi   = lane >> 4;        // 0..3

    // XCD-aware bijective swizzle: 2048 blocks % 8 == 0
    const int swz = (blockIdx.x & 7) * 256 + (blockIdx.x >> 3);
    const int gm0 = (swz >> 5) * 256;  // 64 M-tiles
    const int gn0 = (swz & 31) * 256;  // 32 N-tiles

    // ---- staging geometry (linear LDS dest, pre-swizzled global source) ----
    const int lr8   = lane >> 3;
    const int cswel = ((lane & 7) ^ lr8) * 8;          // swizzled k-elem offset
    const int rbase = wid * 8 + lr8;                   // 0..63
    const u16* gAr = A  + (size_t)(gm0 + rbase) * K_ + cswel;
    const u16* gBr = Bt + (size_t)(gn0 + rbase) * K_ + cswel;

    auto STAGE = [&](const u16* g, int ldsu, int kt) {
        u16* d = sm + ldsu + wid * 512 + lane * 8;
        const u16* s = g + kt;
        __builtin_amdgcn_global_load_lds(GPTR(s),             LPTR(d),        16, 0, 0);
        __builtin_amdgcn_global_load_lds(GPTR(s + 64 * 2048), LPTR(d + 4096), 16, 0, 0);
    };

    // ---- read geometry (zero measured conflicts) ----
    const int c0 = ((hi ^ (lane & 7)) << 4);
    const int rowbyteA = (wm * 128 + (lane & 15)) * 128;
    const int rowbyteB = (wn * 64  + (lane & 15)) * 128;

#define RA(bufr, m, kk) (*(const short8*)(smc + (bufr)*32768 + rowbyteA + (m)*2048 + (c0 ^ ((kk) << 6))))
#define RB(bufr, n, kk) (*(const short8*)(smc + 65536 + (bufr)*32768 + rowbyteB + (n)*2048 + (c0 ^ ((kk) << 6))))

    f32x4 acc[8][4] = {};
    short8 a0[4][2], a1[4][2], b0[2][2], b1[2][2];

#define MFMA_BLK(AF, BF, MO, NO)                                                   \
    do {                                                                           \
        _Pragma("unroll") for (int kk = 0; kk < 2; ++kk)                           \
        _Pragma("unroll") for (int m = 0; m < 4; ++m)                              \
        _Pragma("unroll") for (int n = 0; n < 2; ++n)                              \
            acc[m + MO][n + NO] = __builtin_amdgcn_mfma_f32_16x16x32_bf16(         \
                AF[m][kk], BF[n][kk], acc[m + MO][n + NO], 0, 0, 0);               \
    } while (0)

#define READ_A0B0(bufr)                                                            \
    do {                                                                           \
        _Pragma("unroll") for (int m = 0; m < 4; ++m) {                            \
            a0[m][0] = RA(bufr, m, 0); a0[m][1] = RA(bufr, m, 1); }                \
        _Pragma("unroll") for (int n = 0; n < 2; ++n) {                            \
            b0[n][0] = RB(bufr, n, 0); b0[n][1] = RB(bufr, n, 1); }                \
    } while (0)

#define READ_A1(bufr)                                                              \
    do {                                                                           \
        _Pragma("unroll") for (int m = 0; m < 4; ++m) {                            \
            a1[m][0] = RA(bufr, m + 4, 0); a1[m][1] = RA(bufr, m + 4, 1); }        \
    } while (0)

#define READ_B1(bufr)                                                              \
    do {                                                                           \
        _Pragma("unroll") for (int n = 0; n < 2; ++n) {                            \
            b1[n][0] = RB(bufr, n + 2, 0); b1[n][1] = RB(bufr, n + 2, 1); }        \
    } while (0)

#define PH_SYNC()  do { SB0(); BAR(); } while (0)
#define PH_TAIL()  do { SB0(); LGKM0(); SB0(); BAR(); } while (0)
#define PRIO_MFMA(AF, BF, MO, NO)                                                  \
    do { __builtin_amdgcn_s_setprio(1); MFMA_BLK(AF, BF, MO, NO);                  \
         __builtin_amdgcn_s_setprio(0); } while (0)

    // ---- prologue: stage h0..h5 (Kt0 complete + Kt1 A-halves) ----
    STAGE(gAr,          0,     0);      // A h0 buf0 kt0
    STAGE(gAr + 262144, 8192,  0);      // A h1 buf0
    STAGE(gBr,          32768, 0);      // B h0 buf0
    STAGE(gBr + 262144, 40960, 0);      // B h1 buf0
    STAGE(gAr,          16384, 64);     // A h0 buf1 kt64
    STAGE(gAr + 262144, 24576, 64);     // A h1 buf1
    VM4(); SB0(); BAR();

    for (int it = 0; it < 16; ++it) {
        const bool full = (it < 15);
        const int kt1 = (it * 2 + 1) * 64;
        const int kt2 = (it * 2 + 2) * 64;
        const int kt3 = (it * 2 + 3) * 64;

        // ---- p0: stage B-h0 -> buf1 | read a0,b0 (buf0) | MFMA Q0 ----
        STAGE(gBr, 49152, kt1);
        READ_A0B0(0);
        PH_SYNC();
        PRIO_MFMA(a0, b0, 0, 0);
        PH_TAIL();

        // ---- p1: stage B-h1 -> buf1 | read a1 (buf0) | MFMA Q2 ----
        STAGE(gBr + 262144, 57344, kt1);
        READ_A1(0);
        PH_SYNC();
        PRIO_MFMA(a1, b0, 4, 0);
        PH_TAIL();     // buf0-A reads drained before p2 restage

        // ---- p2: stage A-h0 -> buf0 @kt2 | read b1 (buf0) | MFMA Q1 ----
        if (full) STAGE(gAr, 0, kt2);
        READ_B1(0);
        PH_SYNC();
        PRIO_MFMA(a0, b1, 0, 2);
        PH_TAIL();     // buf0-B reads drained before p4 restage

        // ---- p3: stage A-h1 -> buf0 @kt2 | MFMA Q3 | vmcnt ----
        if (full) STAGE(gAr + 262144, 8192, kt2);
        PH_SYNC();
        PRIO_MFMA(a1, b1, 4, 2);
        SB0(); LGKM0();
        if (full) { VM4(); } else { VM0(); }
        SB0(); BAR();

        // ---- p4: stage B-h0 -> buf0 | read a0,b0 (buf1) | MFMA Q0 ----
        if (full) STAGE(gBr, 32768, kt2);
        READ_A0B0(1);
        PH_SYNC();
        PRIO_MFMA(a0, b0, 0, 0);
        PH_TAIL();

        // ---- p5: stage B-h1 -> buf0 | read a1 (buf1) | MFMA Q2 ----
        if (full) STAGE(gBr + 262144, 40960, kt2);
        READ_A1(1);
        PH_SYNC();
        PRIO_MFMA(a1, b0, 4, 0);
        PH_TAIL();     // buf1-A reads drained before p6 restage

        // ---- p6: stage A-h0 -> buf1 @kt3 | read b1 (buf1) | MFMA Q1 ----
        if (full) STAGE(gAr, 16384, kt3);
        READ_B1(1);
        PH_SYNC();
        PRIO_MFMA(a0, b1, 0, 2);
        PH_TAIL();

        // ---- p7: stage A-h1 -> buf1 @kt3 | MFMA Q3 | vmcnt ----
        if (full) STAGE(gAr + 262144, 24576, kt3);
        PH_SYNC();
        PRIO_MFMA(a1, b1, 4, 2);
        SB0(); LGKM0();
        if (full) { VM4(); }
        SB0(); BAR();
    }

    // ---- epilogue: C/D layout col=lane&15, row=hi*4+i ----
    const int orow0 = gm0 + wm * 128 + hi * 4;
    const int ocol0 = gn0 + wn * 64 + (lane & 15);
#pragma unroll
    for (int n = 0; n < 4; ++n) {
        const float bvv = bias[ocol0 + n * 16];
#pragma unroll
        for (int m = 0; m < 8; ++m) {
#pragma unroll
            for (int i = 0; i < 4; ++i) {
                C[(size_t)(orow0 + m * 16 + i) * N_ + (ocol0 + n * 16)] = acc[m][n][i] + bvv;
            }
        }
    }
#undef RA
#undef RB
#undef MFMA_BLK
#undef READ_A0B0
#undef READ_A1
#undef READ_B1
#undef PH_SYNC
#undef PH_TAIL
#undef PRIO_MFMA
}

// ---------------------------------------------------------------------------
// Workspace layout (bytes):
//   [0,8)            : thr (double)
//   [1024, 9216)     : 1024 fp64 partials
//   [16384, +32MiB)  : wt  bf16 [N=8192][K=2048]
//   [wt_end, +64MiB) : xn  bf16 [M=16384][K=2048]
// ---------------------------------------------------------------------------
extern "C" void kernel_launch(void* const* d_in, const int* in_sizes, int n_in,
                              void* d_out, int out_size, void* d_ws, size_t ws_size,
                              hipStream_t stream)
{
    const float* x     = (const float*)d_in[0];
    const float* w     = (const float*)d_in[1];
    const float* bias  = (const float*)d_in[2];
    const float* gamma = (const float*)d_in[3];
    float* out = (float*)d_out;

    char* ws = (char*)d_ws;
    double* thr      = (double*)(ws);
    double* partials = (double*)(ws + 1024);
    u16*    wt       = (u16*)(ws + 16384);
    u16*    xn       = (u16*)(ws + 16384 + NW_ * 2);

    abssum_kernel   <<<1024,  256,  0, stream>>>(w, partials);
    finalize_thr    <<<1,     1024, 0, stream>>>(partials, thr);
    ternarize_kernel<<<16384, 256,  0, stream>>>(w, thr, wt);
    rmsnorm_kernel  <<<M_,    256,  0, stream>>>(x, gamma, xn);
    gemm_bt_kernel  <<<(M_/256)*(N_/256), 512, 0, stream>>>(xn, wt, bias, out);
}